// Round 1
// baseline (47575.171 us; speedup 1.0000x reference)
//
#include <hip/hip_runtime.h>
#include <math.h>

#define LNUM 12
#define HNUM 12
#define EMB 768
#define TSEQ 1024
#define BBATCH 8
#define VOCAB 50257
#define NTOK (BBATCH*TSEQ)   // 8192

typedef unsigned short u16;
typedef __bf16 bf16_8 __attribute__((ext_vector_type(8)));
typedef float f32x4 __attribute__((ext_vector_type(4)));

__device__ __forceinline__ u16 f2bf(float f){
  unsigned u = __float_as_uint(f);
  u += 0x7fffu + ((u >> 16) & 1u);
  return (u16)(u >> 16);
}
__device__ __forceinline__ float wred(float v){
  #pragma unroll
  for (int m = 32; m; m >>= 1) v += __shfl_xor(v, m, 64);
  return v;
}

#define GLOAD_LDS16(g, l) \
  __builtin_amdgcn_global_load_lds((const __attribute__((address_space(1))) void*)(g), \
                                   (__attribute__((address_space(3))) void*)(l), 16, 0, 0)

// ---------------- weight convert + transpose: src f32 [L][K][N] -> dst bf16 [L][N][K]
__global__ __launch_bounds__(256) void tcvt_kernel(const float* __restrict__ src,
                                                   u16* __restrict__ dst, int K, int N){
  __shared__ float tile[32][33];
  size_t off = (size_t)blockIdx.z * K * N;
  const float* s = src + off;
  u16* d = dst + off;
  int n0 = blockIdx.x * 32, k0 = blockIdx.y * 32;
  int tx = threadIdx.x & 31, ty = threadIdx.x >> 5;
  #pragma unroll
  for (int i = 0; i < 4; i++)
    tile[ty + i*8][tx] = s[(size_t)(k0 + ty + i*8) * N + n0 + tx];
  __syncthreads();
  #pragma unroll
  for (int i = 0; i < 4; i++){
    int n = ty + i*8;
    d[(size_t)(n0 + n) * K + k0 + tx] = f2bf(tile[tx][n]);
  }
}

// ---------------- embedding
__global__ __launch_bounds__(256) void embed_kernel(const int* __restrict__ x,
    const float* __restrict__ tok, const float* __restrict__ pos, float* __restrict__ h){
  int row = blockIdx.x;
  int t = row & (TSEQ - 1);
  int id = x[row];
  const float* te = tok + (size_t)id * EMB;
  const float* pe = pos + (size_t)t * EMB;
  float* hr = h + (size_t)row * EMB;
  for (int i = threadIdx.x; i < EMB; i += 256) hr[i] = te[i] + pe[i];
}

// ---------------- layernorm (row-per-block).  OBF: bf16 out.  LAST: only last token rows.
template<int OBF, int LAST>
__global__ __launch_bounds__(256) void ln_kernel(const float* __restrict__ x,
    const float* __restrict__ g, const float* __restrict__ b, void* __restrict__ out){
  int orow, row;
  if (LAST){ orow = blockIdx.x; row = blockIdx.x * TSEQ + (TSEQ - 1); }
  else     { orow = row = blockIdx.x; }
  const float* xr = x + (size_t)row * EMB;
  int tid = threadIdx.x;
  int wave = tid >> 6, lane = tid & 63;
  float v[3];
  float s = 0.f;
  #pragma unroll
  for (int i = 0; i < 3; i++){ v[i] = xr[tid + i*256]; s += v[i]; }
  __shared__ float red[4];
  s = wred(s);
  if (lane == 0) red[wave] = s;
  __syncthreads();
  float mu = (red[0] + red[1] + red[2] + red[3]) * (1.f / EMB);
  float ss = 0.f;
  #pragma unroll
  for (int i = 0; i < 3; i++){ float d = v[i] - mu; ss += d * d; }
  __syncthreads();
  ss = wred(ss);
  if (lane == 0) red[wave] = ss;
  __syncthreads();
  float var = (red[0] + red[1] + red[2] + red[3]) * (1.f / EMB);
  float rs = rsqrtf(var + 1e-5f);
  #pragma unroll
  for (int i = 0; i < 3; i++){
    int e = tid + i*256;
    float o = g[e] * (v[i] - mu) * rs + b[e];
    if (OBF) ((u16*)out)[(size_t)orow * EMB + e] = f2bf(o);
    else     ((float*)out)[(size_t)orow * EMB + e] = o;
  }
}

// ---------------- bf16 MFMA GEMM, A[M][K] bf16 row-major, Bt[N][K] bf16 row-major.
// EPI 0: f32 out + bias ; EPI 1: f32 out + bias + resid ; EPI 2: bf16 out + bias + gelu
template<int EPI>
__global__ __launch_bounds__(256) void gemm_bt(const u16* __restrict__ A,
    const u16* __restrict__ Bt, const float* __restrict__ bias,
    const float* __restrict__ resid, void* __restrict__ outp, int K, int N){
  __shared__ __align__(16) u16 lA[128*32];
  __shared__ __align__(16) u16 lB[128*32];
  const int tid = threadIdx.x;
  const int wave = tid >> 6, lane = tid & 63;
  const int bm = blockIdx.y, bn = blockIdx.x;
  const int wm = wave >> 1, wn = wave & 1;

  const u16* ga = A  + (size_t)(bm*128 + wave*32 + (lane >> 2)) * K + (lane & 3) * 8;
  const u16* gb = Bt + (size_t)(bn*128 + wave*32 + (lane >> 2)) * K + (lane & 3) * 8;
  u16* la = lA + wave * 32 * 32;   // wave-uniform LDS base (32 rows x 32 k)
  u16* lb = lB + wave * 32 * 32;

  f32x4 acc[4][4];
  #pragma unroll
  for (int i = 0; i < 4; i++)
    #pragma unroll
    for (int j = 0; j < 4; j++){ f32x4 z = {0.f,0.f,0.f,0.f}; acc[i][j] = z; }

  const bf16_8* pa = (const bf16_8*)(lA + ((wm*64) + (lane & 15)) * 32 + (lane >> 4) * 8);
  const bf16_8* pb = (const bf16_8*)(lB + ((wn*64) + (lane & 15)) * 32 + (lane >> 4) * 8);

  for (int k0 = 0; k0 < K; k0 += 32){
    GLOAD_LDS16(ga,                 la);
    GLOAD_LDS16(ga + (size_t)16*K,  la + 16*32);
    GLOAD_LDS16(gb,                 lb);
    GLOAD_LDS16(gb + (size_t)16*K,  lb + 16*32);
    ga += 32; gb += 32;
    __syncthreads();               // drains vmcnt -> LDS tile valid
    bf16_8 af[4], bfv[4];
    #pragma unroll
    for (int i = 0; i < 4; i++){ af[i] = pa[i*64]; bfv[i] = pb[i*64]; }
    #pragma unroll
    for (int mi = 0; mi < 4; mi++)
      #pragma unroll
      for (int ni = 0; ni < 4; ni++)
        acc[mi][ni] = __builtin_amdgcn_mfma_f32_16x16x32_bf16(af[mi], bfv[ni], acc[mi][ni], 0, 0, 0);
    __syncthreads();               // all reads done before next stage overwrites
  }

  const int colb = bn*128 + wn*64;
  const int rowb = bm*128 + wm*64;
  #pragma unroll
  for (int ni = 0; ni < 4; ni++){
    int col = colb + ni*16 + (lane & 15);
    float bv = bias[col];
    #pragma unroll
    for (int mi = 0; mi < 4; mi++){
      #pragma unroll
      for (int j = 0; j < 4; j++){
        int row = rowb + mi*16 + (lane >> 4) * 4 + j;
        float v = acc[mi][ni][j] + bv;
        if (EPI == 1) v += resid[(size_t)row * N + col];
        if (EPI == 2){
          float y = 0.7978845608028654f * (v + 0.044715f * v * v * v);
          float e = __expf(fminf(2.f * y, 80.f));
          v = v * e / (e + 1.f);
        }
        if (EPI == 2) ((u16*)outp)[(size_t)row * N + col] = f2bf(v);
        else          ((float*)outp)[(size_t)row * N + col] = v;
      }
    }
  }
}

// ---------------- causal attention, one wave per query row. lane = d (DH=64).
__global__ __launch_bounds__(256) void attn_kernel(const float* __restrict__ qkv,
                                                   u16* __restrict__ ctx){
  int wave = threadIdx.x >> 6, lane = threadIdx.x & 63;
  int t = blockIdx.x * 4 + wave;
  int bh = blockIdx.y;
  int b = bh / HNUM, hh = bh % HNUM;
  const float* base = qkv + (size_t)b * TSEQ * 2304;
  float q = base[(size_t)t * 2304 + hh*64 + lane] * 0.125f;  // 1/sqrt(64)
  const float* kp = base + 768  + hh*64 + lane;
  const float* vp = base + 1536 + hh*64 + lane;
  float m = -1e30f, l = 0.f, acc = 0.f;
  for (int j = 0; j <= t; j++){
    float kv = kp[(size_t)j * 2304];
    float vv = vp[(size_t)j * 2304];
    float s = q * kv;
    #pragma unroll
    for (int msk = 32; msk; msk >>= 1) s += __shfl_xor(s, msk, 64);
    float nm = fmaxf(m, s);
    float c = __expf(m - nm);
    float p = __expf(s - nm);
    l = l * c + p;
    acc = acc * c + p * vv;
    m = nm;
  }
  ctx[((size_t)(b * TSEQ + t)) * EMB + hh*64 + lane] = f2bf(acc / l);
}

// ---------------- final logits: out[b][v] = dot(last[b], tok[v]); one wave per v
__global__ __launch_bounds__(256) void logits_kernel(const float* __restrict__ last,
    const float* __restrict__ tok, float* __restrict__ out){
  __shared__ float ls[BBATCH * EMB];
  for (int i = threadIdx.x; i < BBATCH * EMB; i += 256) ls[i] = last[i];
  __syncthreads();
  int wave = threadIdx.x >> 6, lane = threadIdx.x & 63;
  int v = blockIdx.x * 4 + wave;
  if (v >= VOCAB) return;
  const float* tp = tok + (size_t)v * EMB;
  float acc[BBATCH];
  #pragma unroll
  for (int b = 0; b < BBATCH; b++) acc[b] = 0.f;
  #pragma unroll
  for (int i = 0; i < EMB/64; i++){
    float tv = tp[i*64 + lane];
    #pragma unroll
    for (int b = 0; b < BBATCH; b++) acc[b] += tv * ls[b*EMB + i*64 + lane];
  }
  #pragma unroll
  for (int b = 0; b < BBATCH; b++){
    float r = wred(acc[b]);
    if (lane == 0) out[(size_t)b * VOCAB + v] = r;
  }
}

extern "C" void kernel_launch(void* const* d_in, const int* in_sizes, int n_in,
                              void* d_out, int out_size, void* d_ws, size_t ws_size,
                              hipStream_t stream){
  const int*   x    = (const int*)  d_in[0];
  const float* tok  = (const float*)d_in[1];
  const float* pos  = (const float*)d_in[2];
  const float* ln1g = (const float*)d_in[3];
  const float* ln1b = (const float*)d_in[4];
  const float* Wqkv = (const float*)d_in[5];
  const float* bqkv = (const float*)d_in[6];
  const float* Wo   = (const float*)d_in[7];
  const float* bo   = (const float*)d_in[8];
  const float* ln2g = (const float*)d_in[9];
  const float* ln2b = (const float*)d_in[10];
  const float* W1   = (const float*)d_in[11];
  const float* b1   = (const float*)d_in[12];
  const float* W2   = (const float*)d_in[13];
  const float* b2   = (const float*)d_in[14];
  const float* lnfg = (const float*)d_in[15];
  const float* lnfb = (const float*)d_in[16];

  char* p = (char*)d_ws;
  u16* wqkvT = (u16*)p;  p += (size_t)LNUM*2304*768*2;
  u16* woT   = (u16*)p;  p += (size_t)LNUM*768*768*2;
  u16* w1T   = (u16*)p;  p += (size_t)LNUM*3072*768*2;
  u16* w2T   = (u16*)p;  p += (size_t)LNUM*768*3072*2;
  float* h   = (float*)p; p += (size_t)NTOK*EMB*4;
  u16* abuf  = (u16*)p;  p += (size_t)NTOK*EMB*2;
  void* tmp  = (void*)p; p += (size_t)NTOK*2304*4;   // qkv f32 / ff bf16 union
  float* lastb = (float*)p; p += (size_t)BBATCH*EMB*4;
  if (ws_size < (size_t)(p - (char*)d_ws)) return;

  tcvt_kernel<<<dim3(2304/32, 768/32, LNUM), 256, 0, stream>>>(Wqkv, wqkvT, 768, 2304);
  tcvt_kernel<<<dim3(768/32,  768/32, LNUM), 256, 0, stream>>>(Wo,   woT,   768, 768);
  tcvt_kernel<<<dim3(3072/32, 768/32, LNUM), 256, 0, stream>>>(W1,   w1T,   768, 3072);
  tcvt_kernel<<<dim3(768/32, 3072/32, LNUM), 256, 0, stream>>>(W2,   w2T,   3072, 768);
  embed_kernel<<<NTOK, 256, 0, stream>>>(x, tok, pos, h);

  float* qkv = (float*)tmp;
  u16*   ff  = (u16*)tmp;
  for (int l = 0; l < LNUM; l++){
    ln_kernel<1,0><<<NTOK, 256, 0, stream>>>(h, ln1g + l*EMB, ln1b + l*EMB, abuf);
    gemm_bt<0><<<dim3(2304/128, NTOK/128), 256, 0, stream>>>(
        abuf, wqkvT + (size_t)l*2304*768, bqkv + (size_t)l*2304, nullptr, qkv, 768, 2304);
    attn_kernel<<<dim3(TSEQ/4, BBATCH*HNUM), 256, 0, stream>>>(qkv, abuf);
    gemm_bt<1><<<dim3(768/128, NTOK/128), 256, 0, stream>>>(
        abuf, woT + (size_t)l*768*768, bo + (size_t)l*768, h, h, 768, 768);
    ln_kernel<1,0><<<NTOK, 256, 0, stream>>>(h, ln2g + l*EMB, ln2b + l*EMB, abuf);
    gemm_bt<2><<<dim3(3072/128, NTOK/128), 256, 0, stream>>>(
        abuf, w1T + (size_t)l*3072*768, b1 + (size_t)l*3072, nullptr, ff, 768, 3072);
    gemm_bt<1><<<dim3(768/128, NTOK/128), 256, 0, stream>>>(
        ff, w2T + (size_t)l*768*3072, b2 + (size_t)l*768, h, h, 3072, 768);
  }
  ln_kernel<0,1><<<BBATCH, 256, 0, stream>>>(h, lnfg, lnfb, lastb);
  logits_kernel<<<(VOCAB + 3)/4, 256, 0, stream>>>(lastb, tok, (float*)d_out);
}

// Round 2
// 4333.409 us; speedup vs baseline: 10.9787x; 10.9787x over previous
//
#include <hip/hip_runtime.h>
#include <math.h>

#define LNUM 12
#define HNUM 12
#define EMB 768
#define TSEQ 1024
#define BBATCH 8
#define VOCAB 50257
#define NTOK (BBATCH*TSEQ)   // 8192

typedef unsigned short u16;
typedef __bf16 bf16_8 __attribute__((ext_vector_type(8)));
typedef float f32x4 __attribute__((ext_vector_type(4)));

__device__ __forceinline__ u16 f2bf(float f){
  unsigned u = __float_as_uint(f);
  u += 0x7fffu + ((u >> 16) & 1u);
  return (u16)(u >> 16);
}
__device__ __forceinline__ float wred(float v){
  #pragma unroll
  for (int m = 32; m; m >>= 1) v += __shfl_xor(v, m, 64);
  return v;
}

#define GLOAD_LDS16(g, l) \
  __builtin_amdgcn_global_load_lds((const __attribute__((address_space(1))) void*)(g), \
                                   (__attribute__((address_space(3))) void*)(l), 16, 0, 0)

// ---------------- weight convert + transpose: src f32 [L][K][N] -> dst bf16 [L][N][K]
__global__ __launch_bounds__(256) void tcvt_kernel(const float* __restrict__ src,
                                                   u16* __restrict__ dst, int K, int N){
  __shared__ float tile[32][33];
  size_t off = (size_t)blockIdx.z * K * N;
  const float* s = src + off;
  u16* d = dst + off;
  int n0 = blockIdx.x * 32, k0 = blockIdx.y * 32;
  int tx = threadIdx.x & 31, ty = threadIdx.x >> 5;
  #pragma unroll
  for (int i = 0; i < 4; i++)
    tile[ty + i*8][tx] = s[(size_t)(k0 + ty + i*8) * N + n0 + tx];
  __syncthreads();
  #pragma unroll
  for (int i = 0; i < 4; i++){
    int n = ty + i*8;
    d[(size_t)(n0 + n) * K + k0 + tx] = f2bf(tile[tx][n]);
  }
}

// ---------------- embedding
__global__ __launch_bounds__(256) void embed_kernel(const int* __restrict__ x,
    const float* __restrict__ tok, const float* __restrict__ pos, float* __restrict__ h){
  int row = blockIdx.x;
  int t = row & (TSEQ - 1);
  int id = x[row];
  const float* te = tok + (size_t)id * EMB;
  const float* pe = pos + (size_t)t * EMB;
  float* hr = h + (size_t)row * EMB;
  for (int i = threadIdx.x; i < EMB; i += 256) hr[i] = te[i] + pe[i];
}

// ---------------- layernorm (row-per-block).  OBF: bf16 out.  LAST: only last token rows.
template<int OBF, int LAST>
__global__ __launch_bounds__(256) void ln_kernel(const float* __restrict__ x,
    const float* __restrict__ g, const float* __restrict__ b, void* __restrict__ out){
  int orow, row;
  if (LAST){ orow = blockIdx.x; row = blockIdx.x * TSEQ + (TSEQ - 1); }
  else     { orow = row = blockIdx.x; }
  const float* xr = x + (size_t)row * EMB;
  int tid = threadIdx.x;
  int wave = tid >> 6, lane = tid & 63;
  float v[3];
  float s = 0.f;
  #pragma unroll
  for (int i = 0; i < 3; i++){ v[i] = xr[tid + i*256]; s += v[i]; }
  __shared__ float red[4];
  s = wred(s);
  if (lane == 0) red[wave] = s;
  __syncthreads();
  float mu = (red[0] + red[1] + red[2] + red[3]) * (1.f / EMB);
  float ss = 0.f;
  #pragma unroll
  for (int i = 0; i < 3; i++){ float d = v[i] - mu; ss += d * d; }
  __syncthreads();
  ss = wred(ss);
  if (lane == 0) red[wave] = ss;
  __syncthreads();
  float var = (red[0] + red[1] + red[2] + red[3]) * (1.f / EMB);
  float rs = rsqrtf(var + 1e-5f);
  #pragma unroll
  for (int i = 0; i < 3; i++){
    int e = tid + i*256;
    float o = g[e] * (v[i] - mu) * rs + b[e];
    if (OBF) ((u16*)out)[(size_t)orow * EMB + e] = f2bf(o);
    else     ((float*)out)[(size_t)orow * EMB + e] = o;
  }
}

// ---------------- bf16 MFMA GEMM, A[M][K] bf16 row-major, Bt[N][K] bf16 row-major.
// EPI 0: f32 out + bias ; EPI 1: f32 out + bias + resid ; EPI 2: bf16 out + bias + gelu
// EPI 3: bf16 out + bias, cols<768 scaled by 0.125 (QKV: fold attn scale into Q)
template<int EPI>
__global__ __launch_bounds__(256) void gemm_bt(const u16* __restrict__ A,
    const u16* __restrict__ Bt, const float* __restrict__ bias,
    const float* __restrict__ resid, void* __restrict__ outp, int K, int N){
  __shared__ __align__(16) u16 lA[128*32];
  __shared__ __align__(16) u16 lB[128*32];
  const int tid = threadIdx.x;
  const int wave = tid >> 6, lane = tid & 63;
  const int bm = blockIdx.y, bn = blockIdx.x;
  const int wm = wave >> 1, wn = wave & 1;

  const u16* ga = A  + (size_t)(bm*128 + wave*32 + (lane >> 2)) * K + (lane & 3) * 8;
  const u16* gb = Bt + (size_t)(bn*128 + wave*32 + (lane >> 2)) * K + (lane & 3) * 8;
  u16* la = lA + wave * 32 * 32;   // wave-uniform LDS base (32 rows x 32 k)
  u16* lb = lB + wave * 32 * 32;

  f32x4 acc[4][4];
  #pragma unroll
  for (int i = 0; i < 4; i++)
    #pragma unroll
    for (int j = 0; j < 4; j++){ f32x4 z = {0.f,0.f,0.f,0.f}; acc[i][j] = z; }

  const bf16_8* pa = (const bf16_8*)(lA + ((wm*64) + (lane & 15)) * 32 + (lane >> 4) * 8);
  const bf16_8* pb = (const bf16_8*)(lB + ((wn*64) + (lane & 15)) * 32 + (lane >> 4) * 8);

  for (int k0 = 0; k0 < K; k0 += 32){
    GLOAD_LDS16(ga,                 la);
    GLOAD_LDS16(ga + (size_t)16*K,  la + 16*32);
    GLOAD_LDS16(gb,                 lb);
    GLOAD_LDS16(gb + (size_t)16*K,  lb + 16*32);
    ga += 32; gb += 32;
    __syncthreads();               // drains vmcnt -> LDS tile valid
    bf16_8 af[4], bfv[4];
    #pragma unroll
    for (int i = 0; i < 4; i++){ af[i] = pa[i*64]; bfv[i] = pb[i*64]; }
    #pragma unroll
    for (int mi = 0; mi < 4; mi++)
      #pragma unroll
      for (int ni = 0; ni < 4; ni++)
        acc[mi][ni] = __builtin_amdgcn_mfma_f32_16x16x32_bf16(af[mi], bfv[ni], acc[mi][ni], 0, 0, 0);
    __syncthreads();               // all reads done before next stage overwrites
  }

  const int colb = bn*128 + wn*64;
  const int rowb = bm*128 + wm*64;
  #pragma unroll
  for (int ni = 0; ni < 4; ni++){
    int col = colb + ni*16 + (lane & 15);
    float bv = bias[col];
    #pragma unroll
    for (int mi = 0; mi < 4; mi++){
      #pragma unroll
      for (int j = 0; j < 4; j++){
        int row = rowb + mi*16 + (lane >> 4) * 4 + j;
        float v = acc[mi][ni][j] + bv;
        if (EPI == 1) v += resid[(size_t)row * N + col];
        if (EPI == 2){
          float y = 0.7978845608028654f * (v + 0.044715f * v * v * v);
          float e = __expf(fminf(2.f * y, 80.f));
          v = v * e / (e + 1.f);
        }
        if (EPI == 3 && col < 768) v *= 0.125f;
        if (EPI == 2 || EPI == 3) ((u16*)outp)[(size_t)row * N + col] = f2bf(v);
        else                      ((float*)outp)[(size_t)row * N + col] = v;
      }
    }
  }
}

// ---------------- V transpose: qkvb bf16 [B*T][2304] (V = cols 1536+) -> vt [bh][64 d][1024 t]
__global__ __launch_bounds__(256) void vtrans_kernel(const u16* __restrict__ qkvb,
                                                     u16* __restrict__ vt){
  int wave = threadIdx.x >> 6, lane = threadIdx.x & 63;
  int bh = blockIdx.y, b = bh / HNUM, h = bh - b * HNUM;
  int t0 = blockIdx.x * 16 + wave * 4;
  const u16* src = qkvb + (size_t)b * TSEQ * 2304 + 1536 + h * 64 + lane;
  unsigned long long w = 0;
  #pragma unroll
  for (int i = 0; i < 4; i++)
    w |= (unsigned long long)src[(size_t)(t0 + i) * 2304] << (16 * i);
  *(unsigned long long*)(vt + ((size_t)bh * 64 + lane) * TSEQ + t0) = w;
}

// ---------------- MFMA flash attention. 4 independent waves/block, 32 q-rows each.
// Swapped QK^T (S^T = K x Q) -> lane-local softmax over keys; P via LDS roundtrip to A-frag.
__global__ __launch_bounds__(256) void attn_mfma(const u16* __restrict__ qkvb,
                                                 const u16* __restrict__ vt,
                                                 u16* __restrict__ ctx){
  __shared__ u16 plds[4][32][40];   // per-wave P tile [32 q][32 keys], stride 40 (80B, 16B-aligned)
  const int wave = threadIdx.x >> 6, lane = threadIdx.x & 63;
  const int g = lane >> 4, q15 = lane & 15;
  const int bh = blockIdx.y, b = bh / HNUM, h = bh - b * HNUM;
  const int q0 = blockIdx.x * 128 + wave * 32;
  const u16* qk  = qkvb + (size_t)b * TSEQ * 2304 + h * 64;
  const u16* vtb = vt + (size_t)bh * 64 * TSEQ;

  // Q fragments (B-operand): lane holds q = q0+qf*16+q15, d = kc*32 + g*8 + 0..7
  bf16_8 qfr[2][2];
  #pragma unroll
  for (int qf = 0; qf < 2; qf++)
    #pragma unroll
    for (int kc = 0; kc < 2; kc++)
      qfr[qf][kc] = *(const bf16_8*)(qk + (size_t)(q0 + qf*16 + q15) * 2304 + kc*32 + g*8);

  f32x4 oacc[2][4];
  #pragma unroll
  for (int i = 0; i < 2; i++)
    #pragma unroll
    for (int j = 0; j < 4; j++){ f32x4 z = {0.f,0.f,0.f,0.f}; oacc[i][j] = z; }
  float mx[2] = {-1e30f, -1e30f}, lsum[2] = {0.f, 0.f};

  for (int kb = 0; kb <= q0; kb += 32){
    // K fragments (A-operand): lane holds key = kb+kf*16+q15, d = kc*32 + g*8 + 0..7
    bf16_8 kfr[2][2];
    #pragma unroll
    for (int kf = 0; kf < 2; kf++)
      #pragma unroll
      for (int kc = 0; kc < 2; kc++)
        kfr[kf][kc] = *(const bf16_8*)(qk + (size_t)(kb + kf*16 + q15) * 2304 + 768 + kc*32 + g*8);

    // S^T tiles: rows=key (lane holds g*4+j), cols=q (lane holds q15)
    f32x4 s[2][2];
    #pragma unroll
    for (int kf = 0; kf < 2; kf++)
      #pragma unroll
      for (int qf = 0; qf < 2; qf++){
        f32x4 z = {0.f,0.f,0.f,0.f};
        #pragma unroll
        for (int kc = 0; kc < 2; kc++)
          z = __builtin_amdgcn_mfma_f32_16x16x32_bf16(kfr[kf][kc], qfr[qf][kc], z, 0, 0, 0);
        s[kf][qf] = z;
      }

    if (kb == q0){   // diagonal block: mask key > q
      #pragma unroll
      for (int kf = 0; kf < 2; kf++)
        #pragma unroll
        for (int qf = 0; qf < 2; qf++)
          #pragma unroll
          for (int j = 0; j < 4; j++)
            if (kf*16 + g*4 + j > qf*16 + q15) s[kf][qf][j] = -1e30f;
    }

    // V^T fragments (B-operand): lane holds d = dc*16+q15, keys kb + g*8 + 0..7
    bf16_8 vb[4];
    #pragma unroll
    for (int dc = 0; dc < 4; dc++)
      vb[dc] = *(const bf16_8*)(vtb + (size_t)(dc*16 + q15) * TSEQ + kb + g*8);

    #pragma unroll
    for (int qf = 0; qf < 2; qf++){
      float sm = -1e30f;
      #pragma unroll
      for (int kf = 0; kf < 2; kf++)
        #pragma unroll
        for (int j = 0; j < 4; j++) sm = fmaxf(sm, s[kf][qf][j]);
      sm = fmaxf(sm, __shfl_xor(sm, 16, 64));
      sm = fmaxf(sm, __shfl_xor(sm, 32, 64));
      float mn = fmaxf(mx[qf], sm);
      float c = __expf(mx[qf] - mn);
      mx[qf] = mn;
      float ps = 0.f;
      unsigned long long pw[2];
      #pragma unroll
      for (int kf = 0; kf < 2; kf++){
        unsigned long long w = 0;
        #pragma unroll
        for (int j = 0; j < 4; j++){
          float p = __expf(s[kf][qf][j] - mn);
          ps += p;
          w |= (unsigned long long)f2bf(p) << (16 * j);
        }
        pw[kf] = w;
      }
      ps += __shfl_xor(ps, 16, 64);
      ps += __shfl_xor(ps, 32, 64);
      lsum[qf] = lsum[qf] * c + ps;
      // P^T regs -> P[q][key] in LDS: row = qf*16+q15, cols kf*16 + g*4 + 0..3
      *(unsigned long long*)&plds[wave][qf*16 + q15][g*4]      = pw[0];
      *(unsigned long long*)&plds[wave][qf*16 + q15][16 + g*4] = pw[1];
      // rescale O (O rows are q = g*4+j -> fetch c from lane q15 = g*4+j)
      #pragma unroll
      for (int j = 0; j < 4; j++){
        float cr = __shfl(c, g*4 + j, 64);
        #pragma unroll
        for (int dc = 0; dc < 4; dc++) oacc[qf][dc][j] *= cr;
      }
    }

    asm volatile("s_waitcnt lgkmcnt(0)" ::: "memory");
    __builtin_amdgcn_sched_barrier(0);

    // P A-fragments: lane holds q = qf*16+q15 row, keys g*8 + 0..7
    bf16_8 pa[2];
    pa[0] = *(const bf16_8*)&plds[wave][q15][g*8];
    pa[1] = *(const bf16_8*)&plds[wave][16 + q15][g*8];
    #pragma unroll
    for (int qf = 0; qf < 2; qf++)
      #pragma unroll
      for (int dc = 0; dc < 4; dc++)
        oacc[qf][dc] = __builtin_amdgcn_mfma_f32_16x16x32_bf16(pa[qf], vb[dc], oacc[qf][dc], 0, 0, 0);
  }

  u16* cb = ctx + ((size_t)(b * TSEQ + q0)) * EMB + h * 64;
  #pragma unroll
  for (int qf = 0; qf < 2; qf++){
    float inv = 1.f / lsum[qf];
    #pragma unroll
    for (int j = 0; j < 4; j++){
      float ir = __shfl(inv, g*4 + j, 64);
      int row = qf*16 + g*4 + j;
      #pragma unroll
      for (int dc = 0; dc < 4; dc++)
        cb[(size_t)row * EMB + dc*16 + q15] = f2bf(oacc[qf][dc][j] * ir);
    }
  }
}

// ---------------- final logits: out[b][v] = dot(last[b], tok[v]); one wave per v
__global__ __launch_bounds__(256) void logits_kernel(const float* __restrict__ last,
    const float* __restrict__ tok, float* __restrict__ out){
  __shared__ float ls[BBATCH * EMB];
  for (int i = threadIdx.x; i < BBATCH * EMB; i += 256) ls[i] = last[i];
  __syncthreads();
  int wave = threadIdx.x >> 6, lane = threadIdx.x & 63;
  int v = blockIdx.x * 4 + wave;
  if (v >= VOCAB) return;
  const float* tp = tok + (size_t)v * EMB;
  float acc[BBATCH];
  #pragma unroll
  for (int b = 0; b < BBATCH; b++) acc[b] = 0.f;
  #pragma unroll
  for (int i = 0; i < EMB/64; i++){
    float tv = tp[i*64 + lane];
    #pragma unroll
    for (int b = 0; b < BBATCH; b++) acc[b] += tv * ls[b*EMB + i*64 + lane];
  }
  #pragma unroll
  for (int b = 0; b < BBATCH; b++){
    float r = wred(acc[b]);
    if (lane == 0) out[(size_t)b * VOCAB + v] = r;
  }
}

extern "C" void kernel_launch(void* const* d_in, const int* in_sizes, int n_in,
                              void* d_out, int out_size, void* d_ws, size_t ws_size,
                              hipStream_t stream){
  const int*   x    = (const int*)  d_in[0];
  const float* tok  = (const float*)d_in[1];
  const float* pos  = (const float*)d_in[2];
  const float* ln1g = (const float*)d_in[3];
  const float* ln1b = (const float*)d_in[4];
  const float* Wqkv = (const float*)d_in[5];
  const float* bqkv = (const float*)d_in[6];
  const float* Wo   = (const float*)d_in[7];
  const float* bo   = (const float*)d_in[8];
  const float* ln2g = (const float*)d_in[9];
  const float* ln2b = (const float*)d_in[10];
  const float* W1   = (const float*)d_in[11];
  const float* b1   = (const float*)d_in[12];
  const float* W2   = (const float*)d_in[13];
  const float* b2   = (const float*)d_in[14];
  const float* lnfg = (const float*)d_in[15];
  const float* lnfb = (const float*)d_in[16];

  char* p = (char*)d_ws;
  u16* wqkvT = (u16*)p;  p += (size_t)LNUM*2304*768*2;
  u16* woT   = (u16*)p;  p += (size_t)LNUM*768*768*2;
  u16* w1T   = (u16*)p;  p += (size_t)LNUM*3072*768*2;
  u16* w2T   = (u16*)p;  p += (size_t)LNUM*768*3072*2;
  float* h   = (float*)p; p += (size_t)NTOK*EMB*4;
  u16* abuf  = (u16*)p;  p += (size_t)NTOK*EMB*2;
  void* tmp  = (void*)p; p += (size_t)NTOK*2304*4;   // qkvb bf16 / ff bf16 union
  u16* vt    = (u16*)p;  p += (size_t)BBATCH*HNUM*64*TSEQ*2;
  float* lastb = (float*)p; p += (size_t)BBATCH*EMB*4;
  if (ws_size < (size_t)(p - (char*)d_ws)) return;

  tcvt_kernel<<<dim3(2304/32, 768/32, LNUM), 256, 0, stream>>>(Wqkv, wqkvT, 768, 2304);
  tcvt_kernel<<<dim3(768/32,  768/32, LNUM), 256, 0, stream>>>(Wo,   woT,   768, 768);
  tcvt_kernel<<<dim3(3072/32, 768/32, LNUM), 256, 0, stream>>>(W1,   w1T,   768, 3072);
  tcvt_kernel<<<dim3(768/32, 3072/32, LNUM), 256, 0, stream>>>(W2,   w2T,   3072, 768);
  embed_kernel<<<NTOK, 256, 0, stream>>>(x, tok, pos, h);

  u16* qkvb = (u16*)tmp;
  u16* ff   = (u16*)tmp;
  for (int l = 0; l < LNUM; l++){
    ln_kernel<1,0><<<NTOK, 256, 0, stream>>>(h, ln1g + l*EMB, ln1b + l*EMB, abuf);
    gemm_bt<3><<<dim3(2304/128, NTOK/128), 256, 0, stream>>>(
        abuf, wqkvT + (size_t)l*2304*768, bqkv + (size_t)l*2304, nullptr, qkvb, 768, 2304);
    vtrans_kernel<<<dim3(TSEQ/16, BBATCH*HNUM), 256, 0, stream>>>(qkvb, vt);
    attn_mfma<<<dim3(TSEQ/128, BBATCH*HNUM), 256, 0, stream>>>(qkvb, vt, abuf);
    gemm_bt<1><<<dim3(768/128, NTOK/128), 256, 0, stream>>>(
        abuf, woT + (size_t)l*768*768, bo + (size_t)l*768, h, h, 768, 768);
    ln_kernel<1,0><<<NTOK, 256, 0, stream>>>(h, ln2g + l*EMB, ln2b + l*EMB, abuf);
    gemm_bt<2><<<dim3(3072/128, NTOK/128), 256, 0, stream>>>(
        abuf, w1T + (size_t)l*3072*768, b1 + (size_t)l*3072, nullptr, ff, 768, 3072);
    gemm_bt<1><<<dim3(768/128, NTOK/128), 256, 0, stream>>>(
        ff, w2T + (size_t)l*768*3072, b2 + (size_t)l*768, h, h, 3072, 768);
  }
  ln_kernel<0,1><<<BBATCH, 256, 0, stream>>>(h, lnfg, lnfb, lastb);
  logits_kernel<<<(VOCAB + 3)/4, 256, 0, stream>>>(lastb, tok, (float*)d_out);
}

// Round 3
// 3934.491 us; speedup vs baseline: 12.0918x; 1.1014x over previous
//
#include <hip/hip_runtime.h>
#include <math.h>

#define LNUM 12
#define HNUM 12
#define EMB 768
#define TSEQ 1024
#define BBATCH 8
#define VOCAB 50257
#define NTOK (BBATCH*TSEQ)   // 8192

typedef unsigned short u16;
typedef __bf16 bf16_8 __attribute__((ext_vector_type(8)));
typedef float f32x4 __attribute__((ext_vector_type(4)));

__device__ __forceinline__ u16 f2bf(float f){
  unsigned u = __float_as_uint(f);
  u += 0x7fffu + ((u >> 16) & 1u);
  return (u16)(u >> 16);
}
__device__ __forceinline__ float wred(float v){
  #pragma unroll
  for (int m = 32; m; m >>= 1) v += __shfl_xor(v, m, 64);
  return v;
}

#define GLOAD_LDS16(g, l) \
  __builtin_amdgcn_global_load_lds((const __attribute__((address_space(1))) void*)(g), \
                                   (__attribute__((address_space(3))) void*)(l), 16, 0, 0)

template<int N> struct WCst { static constexpr int val = N; };

// ---------------- weight convert + transpose: src f32 [L][K][N] -> dst bf16 [L][N][K]
__global__ __launch_bounds__(256) void tcvt_kernel(const float* __restrict__ src,
                                                   u16* __restrict__ dst, int K, int N){
  __shared__ float tile[32][33];
  size_t off = (size_t)blockIdx.z * K * N;
  const float* s = src + off;
  u16* d = dst + off;
  int n0 = blockIdx.x * 32, k0 = blockIdx.y * 32;
  int tx = threadIdx.x & 31, ty = threadIdx.x >> 5;
  #pragma unroll
  for (int i = 0; i < 4; i++)
    tile[ty + i*8][tx] = s[(size_t)(k0 + ty + i*8) * N + n0 + tx];
  __syncthreads();
  #pragma unroll
  for (int i = 0; i < 4; i++){
    int n = ty + i*8;
    d[(size_t)(n0 + n) * K + k0 + tx] = f2bf(tile[tx][n]);
  }
}

// ---------------- embedding
__global__ __launch_bounds__(256) void embed_kernel(const int* __restrict__ x,
    const float* __restrict__ tok, const float* __restrict__ pos, float* __restrict__ h){
  int row = blockIdx.x;
  int t = row & (TSEQ - 1);
  int id = x[row];
  const float* te = tok + (size_t)id * EMB;
  const float* pe = pos + (size_t)t * EMB;
  float* hr = h + (size_t)row * EMB;
  for (int i = threadIdx.x; i < EMB; i += 256) hr[i] = te[i] + pe[i];
}

// ---------------- layernorm (row-per-block).  OBF: bf16 out.  LAST: only last token rows.
template<int OBF, int LAST>
__global__ __launch_bounds__(256) void ln_kernel(const float* __restrict__ x,
    const float* __restrict__ g, const float* __restrict__ b, void* __restrict__ out){
  int orow, row;
  if (LAST){ orow = blockIdx.x; row = blockIdx.x * TSEQ + (TSEQ - 1); }
  else     { orow = row = blockIdx.x; }
  const float* xr = x + (size_t)row * EMB;
  int tid = threadIdx.x;
  int wave = tid >> 6, lane = tid & 63;
  float v[3];
  float s = 0.f;
  #pragma unroll
  for (int i = 0; i < 3; i++){ v[i] = xr[tid + i*256]; s += v[i]; }
  __shared__ float red[4];
  s = wred(s);
  if (lane == 0) red[wave] = s;
  __syncthreads();
  float mu = (red[0] + red[1] + red[2] + red[3]) * (1.f / EMB);
  float ss = 0.f;
  #pragma unroll
  for (int i = 0; i < 3; i++){ float d = v[i] - mu; ss += d * d; }
  __syncthreads();
  ss = wred(ss);
  if (lane == 0) red[wave] = ss;
  __syncthreads();
  float var = (red[0] + red[1] + red[2] + red[3]) * (1.f / EMB);
  float rs = rsqrtf(var + 1e-5f);
  #pragma unroll
  for (int i = 0; i < 3; i++){
    int e = tid + i*256;
    float o = g[e] * (v[i] - mu) * rs + b[e];
    if (OBF) ((u16*)out)[(size_t)orow * EMB + e] = f2bf(o);
    else     ((float*)out)[(size_t)orow * EMB + e] = o;
  }
}

// ---------------- ring-pipelined bf16 MFMA GEMM. A[M][K] bf16, Bt[N][K] bf16.
// 512 thr / 8 waves (2M x 4N), BK=32, 4-slot LDS ring, counted vmcnt, raw s_barrier.
// EPI 1: f32 out + bias + resid ; EPI 2: bf16 out + bias + gelu ; EPI 3: bf16 out + bias, cols<768 *0.125
template<int BM, int EPI>
__global__ __launch_bounds__(512, 2) void gemm_ring(const u16* __restrict__ A,
    const u16* __restrict__ Bt, const float* __restrict__ bias,
    const float* __restrict__ resid, void* __restrict__ outp, int K, int N){
  constexpr int LA = BM / 128;          // A loads per tile (8KB each)
  constexpr int LOADS = LA + 2;         // loads per K-tile
  constexpr int SLOTE = (BM + 256) * 32; // u16 elems per ring slot
  constexpr int M_REP = BM / 32;
  __shared__ __align__(16) u16 lds[4 * SLOTE];
  const int tid = threadIdx.x;
  const int wave = tid >> 6, lane = tid & 63;
  const int q15 = lane & 15, ko = lane >> 4;
  const int wm = wave >> 2, wn = wave & 3;
  const int bm = blockIdx.y, bn = blockIdx.x;
  const int NT = K >> 5;

  const u16* gA0 = A  + (size_t)(bm*BM  + (tid >> 2)) * K + (tid & 3) * 8;
  const u16* gB0 = Bt + (size_t)(bn*256 + (tid >> 2)) * K + (tid & 3) * 8;
  u16* ldsW = lds + (tid >> 6) * 512;   // wave-uniform chunk base

#define STAGE(tt) do { \
    int _t = (tt); \
    const u16* _sa = gA0 + (size_t)_t * 32; \
    const u16* _sb = gB0 + (size_t)_t * 32; \
    u16* _ls = ldsW + (_t & 3) * SLOTE; \
    _Pragma("unroll") \
    for (int _i = 0; _i < LA; _i++) \
      GLOAD_LDS16(_sa + (size_t)_i * 128 * K, _ls + _i * 4096); \
    _Pragma("unroll") \
    for (int _i = 0; _i < 2; _i++) \
      GLOAD_LDS16(_sb + (size_t)_i * 128 * K, _ls + BM*32 + _i * 4096); \
  } while (0)

  f32x4 acc[M_REP][4];
  #pragma unroll
  for (int i = 0; i < M_REP; i++)
    #pragma unroll
    for (int j = 0; j < 4; j++){ f32x4 z = {0.f,0.f,0.f,0.f}; acc[i][j] = z; }

  const int aoff = (wm*(BM/2) + q15) * 32 + ko * 8;
  const int boff = BM*32 + (wn*64 + q15) * 32 + ko * 8;

  auto tile = [&](int t, auto wc, bool dostage){
    if (dostage) STAGE(t + 3);
    const u16* sA = lds + (t & 3) * SLOTE;
    bf16_8 af[M_REP], bfr[4];
    #pragma unroll
    for (int mi = 0; mi < M_REP; mi++) af[mi] = *(const bf16_8*)(sA + aoff + mi * 512);
    #pragma unroll
    for (int ni = 0; ni < 4; ni++)    bfr[ni] = *(const bf16_8*)(sA + boff + ni * 512);
    __builtin_amdgcn_s_setprio(1);
    #pragma unroll
    for (int mi = 0; mi < M_REP; mi++)
      #pragma unroll
      for (int ni = 0; ni < 4; ni++)
        acc[mi][ni] = __builtin_amdgcn_mfma_f32_16x16x32_bf16(af[mi], bfr[ni], acc[mi][ni], 0, 0, 0);
    __builtin_amdgcn_s_setprio(0);
    asm volatile("s_waitcnt vmcnt(%0)" :: "n"(decltype(wc)::val) : "memory");
    __builtin_amdgcn_sched_barrier(0);
    __builtin_amdgcn_s_barrier();
    __builtin_amdgcn_sched_barrier(0);
  };

  // prologue: 3 tiles in flight, confirm tile 0
  STAGE(0); STAGE(1); STAGE(2);
  asm volatile("s_waitcnt vmcnt(%0)" :: "n"(2 * LOADS) : "memory");
  __builtin_amdgcn_sched_barrier(0);
  __builtin_amdgcn_s_barrier();
  __builtin_amdgcn_sched_barrier(0);

  for (int t = 0; t < NT - 3; ++t) tile(t, WCst<2 * LOADS>{}, true);
  tile(NT - 3, WCst<LOADS>{}, false);
  tile(NT - 2, WCst<0>{}, false);
  tile(NT - 1, WCst<0>{}, false);
#undef STAGE

  const int colb = bn*256 + wn*64;
  const int rowb = bm*BM + wm*(BM/2);
  #pragma unroll
  for (int ni = 0; ni < 4; ni++){
    int col = colb + ni*16 + q15;
    float bv = bias[col];
    #pragma unroll
    for (int mi = 0; mi < M_REP; mi++){
      #pragma unroll
      for (int j = 0; j < 4; j++){
        int row = rowb + mi*16 + ko*4 + j;
        float v = acc[mi][ni][j] + bv;
        if (EPI == 1) v += resid[(size_t)row * N + col];
        if (EPI == 2){
          float y = 0.7978845608028654f * (v + 0.044715f * v * v * v);
          float e = __expf(fminf(2.f * y, 80.f));
          v = v * e / (e + 1.f);
        }
        if (EPI == 3 && col < 768) v *= 0.125f;
        if (EPI == 2 || EPI == 3) ((u16*)outp)[(size_t)row * N + col] = f2bf(v);
        else                      ((float*)outp)[(size_t)row * N + col] = v;
      }
    }
  }
}

// ---------------- V transpose: qkvb bf16 [B*T][2304] (V = cols 1536+) -> vt [bh][64 d][1024 t]
__global__ __launch_bounds__(256) void vtrans_kernel(const u16* __restrict__ qkvb,
                                                     u16* __restrict__ vt){
  int wave = threadIdx.x >> 6, lane = threadIdx.x & 63;
  int bh = blockIdx.y, b = bh / HNUM, h = bh - b * HNUM;
  int t0 = blockIdx.x * 16 + wave * 4;
  const u16* src = qkvb + (size_t)b * TSEQ * 2304 + 1536 + h * 64 + lane;
  unsigned long long w = 0;
  #pragma unroll
  for (int i = 0; i < 4; i++)
    w |= (unsigned long long)src[(size_t)(t0 + i) * 2304] << (16 * i);
  *(unsigned long long*)(vt + ((size_t)bh * 64 + lane) * TSEQ + t0) = w;
}

// ---------------- MFMA flash attention. 4 independent waves/block, 64 q-rows each.
// Swapped QK^T -> lane-local softmax; K/V register prefetch; reversed block order.
__global__ __launch_bounds__(256, 2) void attn_mfma(const u16* __restrict__ qkvb,
                                                    const u16* __restrict__ vt,
                                                    u16* __restrict__ ctx){
  __shared__ u16 plds[4][64][40];   // per-wave P tile [64 q][32 keys], stride 40
  const int wave = threadIdx.x >> 6, lane = threadIdx.x & 63;
  const int g = lane >> 4, q15 = lane & 15;
  const int bh = blockIdx.y, b = bh / HNUM, h = bh - b * HNUM;
  const int q0 = ((int)gridDim.x - 1 - (int)blockIdx.x) * 256 + wave * 64;
  const u16* qk  = qkvb + (size_t)b * TSEQ * 2304 + h * 64;
  const u16* vtb = vt + (size_t)bh * 64 * TSEQ;

#define LOADKV(kb_, kd, vd) do { \
    _Pragma("unroll") \
    for (int _kf = 0; _kf < 2; _kf++) \
      _Pragma("unroll") \
      for (int _kc = 0; _kc < 2; _kc++) \
        kd[_kf][_kc] = *(const bf16_8*)(qk + (size_t)((kb_) + _kf*16 + q15) * 2304 + 768 + _kc*32 + g*8); \
    _Pragma("unroll") \
    for (int _dc = 0; _dc < 4; _dc++) \
      vd[_dc] = *(const bf16_8*)(vtb + (size_t)(_dc*16 + q15) * TSEQ + (kb_) + g*8); \
  } while (0)

  // Q fragments (B-operand): lane holds q = q0+qf*16+q15, d = kc*32 + g*8 + 0..7
  bf16_8 qfr[4][2];
  #pragma unroll
  for (int qf = 0; qf < 4; qf++)
    #pragma unroll
    for (int kc = 0; kc < 2; kc++)
      qfr[qf][kc] = *(const bf16_8*)(qk + (size_t)(q0 + qf*16 + q15) * 2304 + kc*32 + g*8);

  f32x4 oacc[4][4];
  #pragma unroll
  for (int i = 0; i < 4; i++)
    #pragma unroll
    for (int j = 0; j < 4; j++){ f32x4 z = {0.f,0.f,0.f,0.f}; oacc[i][j] = z; }
  float mx[4] = {-1e30f,-1e30f,-1e30f,-1e30f}, lsum[4] = {0.f,0.f,0.f,0.f};

  const int kbmax = q0 + 32;
  bf16_8 kcur[2][2], vcur[4];
  LOADKV(0, kcur, vcur);

  for (int kb = 0; kb <= kbmax; kb += 32){
    bf16_8 knxt[2][2], vnxt[4];
    if (kb < kbmax) LOADKV(kb + 32, knxt, vnxt);

    // S^T tiles: rows=key (lane g*4+j), cols=q (lane q15)
    f32x4 s[2][4];
    #pragma unroll
    for (int kf = 0; kf < 2; kf++)
      #pragma unroll
      for (int qf = 0; qf < 4; qf++){
        f32x4 z = {0.f,0.f,0.f,0.f};
        z = __builtin_amdgcn_mfma_f32_16x16x32_bf16(kcur[kf][0], qfr[qf][0], z, 0, 0, 0);
        z = __builtin_amdgcn_mfma_f32_16x16x32_bf16(kcur[kf][1], qfr[qf][1], z, 0, 0, 0);
        s[kf][qf] = z;
      }

    if (kb + 31 > q0){   // diagonal region: mask key_abs > q_abs
      #pragma unroll
      for (int kf = 0; kf < 2; kf++)
        #pragma unroll
        for (int qf = 0; qf < 4; qf++)
          #pragma unroll
          for (int j = 0; j < 4; j++)
            if (kb + kf*16 + g*4 + j > q0 + qf*16 + q15) s[kf][qf][j] = -1e30f;
    }

    #pragma unroll
    for (int qf = 0; qf < 4; qf++){
      float sm = -1e30f;
      #pragma unroll
      for (int kf = 0; kf < 2; kf++)
        #pragma unroll
        for (int j = 0; j < 4; j++) sm = fmaxf(sm, s[kf][qf][j]);
      sm = fmaxf(sm, __shfl_xor(sm, 16, 64));
      sm = fmaxf(sm, __shfl_xor(sm, 32, 64));
      float mn = fmaxf(mx[qf], sm);
      float c = __expf(mx[qf] - mn);
      mx[qf] = mn;
      float ps = 0.f;
      unsigned long long pw[2];
      #pragma unroll
      for (int kf = 0; kf < 2; kf++){
        unsigned long long w = 0;
        #pragma unroll
        for (int j = 0; j < 4; j++){
          float p = __expf(s[kf][qf][j] - mn);
          ps += p;
          w |= (unsigned long long)f2bf(p) << (16 * j);
        }
        pw[kf] = w;
      }
      ps += __shfl_xor(ps, 16, 64);
      ps += __shfl_xor(ps, 32, 64);
      lsum[qf] = lsum[qf] * c + ps;
      *(unsigned long long*)&plds[wave][qf*16 + q15][g*4]      = pw[0];
      *(unsigned long long*)&plds[wave][qf*16 + q15][16 + g*4] = pw[1];
      #pragma unroll
      for (int j = 0; j < 4; j++){
        float cr = __shfl(c, g*4 + j, 64);
        #pragma unroll
        for (int dc = 0; dc < 4; dc++) oacc[qf][dc][j] *= cr;
      }
    }

    asm volatile("s_waitcnt lgkmcnt(0)" ::: "memory");
    __builtin_amdgcn_sched_barrier(0);

    bf16_8 pa[4];
    #pragma unroll
    for (int qf = 0; qf < 4; qf++)
      pa[qf] = *(const bf16_8*)&plds[wave][qf*16 + q15][g*8];
    #pragma unroll
    for (int qf = 0; qf < 4; qf++)
      #pragma unroll
      for (int dc = 0; dc < 4; dc++)
        oacc[qf][dc] = __builtin_amdgcn_mfma_f32_16x16x32_bf16(pa[qf], vcur[dc], oacc[qf][dc], 0, 0, 0);

    if (kb < kbmax){
      #pragma unroll
      for (int kf = 0; kf < 2; kf++)
        #pragma unroll
        for (int kc = 0; kc < 2; kc++) kcur[kf][kc] = knxt[kf][kc];
      #pragma unroll
      for (int dc = 0; dc < 4; dc++) vcur[dc] = vnxt[dc];
    }
  }
#undef LOADKV

  u16* cb = ctx + ((size_t)(b * TSEQ + q0)) * EMB + h * 64;
  #pragma unroll
  for (int qf = 0; qf < 4; qf++){
    float inv = 1.f / lsum[qf];
    #pragma unroll
    for (int j = 0; j < 4; j++){
      float ir = __shfl(inv, g*4 + j, 64);
      int row = qf*16 + g*4 + j;
      #pragma unroll
      for (int dc = 0; dc < 4; dc++)
        cb[(size_t)row * EMB + dc*16 + q15] = f2bf(oacc[qf][dc][j] * ir);
    }
  }
}

// ---------------- final logits: out[b][v] = dot(last[b], tok[v]); one wave per v
__global__ __launch_bounds__(256) void logits_kernel(const float* __restrict__ last,
    const float* __restrict__ tok, float* __restrict__ out){
  __shared__ float ls[BBATCH * EMB];
  for (int i = threadIdx.x; i < BBATCH * EMB; i += 256) ls[i] = last[i];
  __syncthreads();
  int wave = threadIdx.x >> 6, lane = threadIdx.x & 63;
  int v = blockIdx.x * 4 + wave;
  if (v >= VOCAB) return;
  const float* tp = tok + (size_t)v * EMB;
  float acc[BBATCH];
  #pragma unroll
  for (int b = 0; b < BBATCH; b++) acc[b] = 0.f;
  #pragma unroll
  for (int i = 0; i < EMB/64; i++){
    float tv = tp[i*64 + lane];
    #pragma unroll
    for (int b = 0; b < BBATCH; b++) acc[b] += tv * ls[b*EMB + i*64 + lane];
  }
  #pragma unroll
  for (int b = 0; b < BBATCH; b++){
    float r = wred(acc[b]);
    if (lane == 0) out[(size_t)b * VOCAB + v] = r;
  }
}

extern "C" void kernel_launch(void* const* d_in, const int* in_sizes, int n_in,
                              void* d_out, int out_size, void* d_ws, size_t ws_size,
                              hipStream_t stream){
  const int*   x    = (const int*)  d_in[0];
  const float* tok  = (const float*)d_in[1];
  const float* pos  = (const float*)d_in[2];
  const float* ln1g = (const float*)d_in[3];
  const float* ln1b = (const float*)d_in[4];
  const float* Wqkv = (const float*)d_in[5];
  const float* bqkv = (const float*)d_in[6];
  const float* Wo   = (const float*)d_in[7];
  const float* bo   = (const float*)d_in[8];
  const float* ln2g = (const float*)d_in[9];
  const float* ln2b = (const float*)d_in[10];
  const float* W1   = (const float*)d_in[11];
  const float* b1   = (const float*)d_in[12];
  const float* W2   = (const float*)d_in[13];
  const float* b2   = (const float*)d_in[14];
  const float* lnfg = (const float*)d_in[15];
  const float* lnfb = (const float*)d_in[16];

  char* p = (char*)d_ws;
  u16* wqkvT = (u16*)p;  p += (size_t)LNUM*2304*768*2;
  u16* woT   = (u16*)p;  p += (size_t)LNUM*768*768*2;
  u16* w1T   = (u16*)p;  p += (size_t)LNUM*3072*768*2;
  u16* w2T   = (u16*)p;  p += (size_t)LNUM*768*3072*2;
  float* h   = (float*)p; p += (size_t)NTOK*EMB*4;
  u16* abuf  = (u16*)p;  p += (size_t)NTOK*EMB*2;
  void* tmp  = (void*)p; p += (size_t)NTOK*2304*4;   // qkvb bf16 / ff bf16 union
  u16* vt    = (u16*)p;  p += (size_t)BBATCH*HNUM*64*TSEQ*2;
  float* lastb = (float*)p; p += (size_t)BBATCH*EMB*4;
  if (ws_size < (size_t)(p - (char*)d_ws)) return;

  tcvt_kernel<<<dim3(2304/32, 768/32, LNUM), 256, 0, stream>>>(Wqkv, wqkvT, 768, 2304);
  tcvt_kernel<<<dim3(768/32,  768/32, LNUM), 256, 0, stream>>>(Wo,   woT,   768, 768);
  tcvt_kernel<<<dim3(3072/32, 768/32, LNUM), 256, 0, stream>>>(W1,   w1T,   768, 3072);
  tcvt_kernel<<<dim3(768/32, 3072/32, LNUM), 256, 0, stream>>>(W2,   w2T,   3072, 768);
  embed_kernel<<<NTOK, 256, 0, stream>>>(x, tok, pos, h);

  u16* qkvb = (u16*)tmp;
  u16* ff   = (u16*)tmp;
  for (int l = 0; l < LNUM; l++){
    ln_kernel<1,0><<<NTOK, 256, 0, stream>>>(h, ln1g + l*EMB, ln1b + l*EMB, abuf);
    gemm_ring<128,3><<<dim3(2304/256, NTOK/128), 512, 0, stream>>>(
        abuf, wqkvT + (size_t)l*2304*768, bqkv + (size_t)l*2304, nullptr, qkvb, 768, 2304);
    vtrans_kernel<<<dim3(TSEQ/16, BBATCH*HNUM), 256, 0, stream>>>(qkvb, vt);
    attn_mfma<<<dim3(TSEQ/256, BBATCH*HNUM), 256, 0, stream>>>(qkvb, vt, abuf);
    gemm_ring<128,1><<<dim3(768/256, NTOK/128), 512, 0, stream>>>(
        abuf, woT + (size_t)l*768*768, bo + (size_t)l*768, h, h, 768, 768);
    ln_kernel<1,0><<<NTOK, 256, 0, stream>>>(h, ln2g + l*EMB, ln2b + l*EMB, abuf);
    gemm_ring<256,2><<<dim3(3072/256, NTOK/256), 512, 0, stream>>>(
        abuf, w1T + (size_t)l*3072*768, b1 + (size_t)l*3072, nullptr, ff, 768, 3072);
    gemm_ring<128,1><<<dim3(768/256, NTOK/128), 512, 0, stream>>>(
        ff, w2T + (size_t)l*768*3072, b2 + (size_t)l*768, h, h, 3072, 768);
  }
  ln_kernel<0,1><<<BBATCH, 256, 0, stream>>>(h, lnfg, lnfb, lastb);
  logits_kernel<<<(VOCAB + 3)/4, 256, 0, stream>>>(lastb, tok, (float*)d_out);
}